// Round 1
// baseline (6756.055 us; speedup 1.0000x reference)
//
#include <hip/hip_runtime.h>
#include <hip/hip_bf16.h>
#include <math.h>

// Problem constants (E83CircularTowerCell): T=2048, B=16, D=1024, n=64, K=3
#define TT 2048
#define BB_ 16
#define DD 1024
#define NN 64
#define KK 3
#define PP 448   // K*2*n + n = 384 + 64

__device__ __forceinline__ float sigmoidf_(float x) {
    return 1.0f / (1.0f + __expf(-x));
}

// ---------------------------------------------------------------------------
// GEMM: kvq[(t*B+b)][p] = sum_d x[t,b,d] * Wcat[p][d]
//   Wcat rows 0..383 = W_kv, rows 384..447 = W_q
// 64x64 tile, 256 threads, 4x4 accumulators per thread, K-chunk = 16.
// ---------------------------------------------------------------------------
__global__ __launch_bounds__(256) void proj_gemm_kernel(
    const float* __restrict__ x,
    const float* __restrict__ Wkv,
    const float* __restrict__ Wq,
    float* __restrict__ kvq)
{
    __shared__ float As[16][68];
    __shared__ float Bs[16][68];

    const int tid = threadIdx.x;
    const int m0 = blockIdx.x * 64;
    const int p0 = blockIdx.y * 64;
    const int tx = tid & 15;
    const int ty = tid >> 4;
    const int lrow = tid >> 2;        // 0..63
    const int lk   = (tid & 3) * 4;   // 0,4,8,12

    const int p = p0 + lrow;
    const float* wrow = (p < 384) ? (Wkv + (size_t)p * DD)
                                  : (Wq  + (size_t)(p - 384) * DD);
    const float* arow = x + (size_t)(m0 + lrow) * DD;

    float acc[4][4] = {};

    for (int kb = 0; kb < DD; kb += 16) {
        const float4 a4 = *(const float4*)(arow + kb + lk);
        const float4 b4 = *(const float4*)(wrow + kb + lk);
        __syncthreads();
        As[lk + 0][lrow] = a4.x; As[lk + 1][lrow] = a4.y;
        As[lk + 2][lrow] = a4.z; As[lk + 3][lrow] = a4.w;
        Bs[lk + 0][lrow] = b4.x; Bs[lk + 1][lrow] = b4.y;
        Bs[lk + 2][lrow] = b4.z; Bs[lk + 3][lrow] = b4.w;
        __syncthreads();
        #pragma unroll
        for (int kk = 0; kk < 16; ++kk) {
            const float4 av = *(const float4*)&As[kk][ty * 4];
            const float4 bv = *(const float4*)&Bs[kk][tx * 4];
            const float a[4] = {av.x, av.y, av.z, av.w};
            const float b[4] = {bv.x, bv.y, bv.z, bv.w};
            #pragma unroll
            for (int ia = 0; ia < 4; ++ia)
                #pragma unroll
                for (int ib = 0; ib < 4; ++ib)
                    acc[ia][ib] += a[ia] * b[ib];
        }
    }

    #pragma unroll
    for (int ia = 0; ia < 4; ++ia) {
        float4 v = make_float4(acc[ia][0], acc[ia][1], acc[ia][2], acc[ia][3]);
        *(float4*)&kvq[(size_t)(m0 + ty * 4 + ia) * PP + p0 + tx * 4] = v;
    }
}

// ---------------------------------------------------------------------------
// Sequential scan. One block per batch b (16 blocks), 192 threads = 3 waves,
// wave w owns state matrix M[w] (64x64) in registers: lane (r,c) holds the
// 8x8 subtile rows 8r..8r+7, cols 8c..8c+7.
//
// gater[k'] = M[(k'+1)%K]  => wave w computes gate sums for wp = (w-1+K)%K
// using its own M[w] dotted with k_norm[wp], publishes via LDS.
// ---------------------------------------------------------------------------
__global__ __launch_bounds__(192) void scan_kernel(
    const float* __restrict__ kvq,
    const float* __restrict__ M_init,
    const float* __restrict__ B_gates,
    float* __restrict__ d_out)
{
    const int b    = blockIdx.x;      // 0..15
    const int tid  = threadIdx.x;
    const int w    = tid >> 6;        // 0..2  (k index this wave owns)
    const int lane = tid & 63;
    const int r    = lane >> 3;       // 0..7
    const int c    = lane & 7;        // 0..7
    const int wp   = (w + 2) % 3;     // (w-1) mod 3: gate target of this wave

    __shared__ float kn_lds[3][64];
    __shared__ float v_lds[3][64];
    __shared__ float rs_lds[3][64];
    __shared__ float cs_lds[3][64];
    __shared__ float q_lds[64];

    // Load initial state (zeros per setup, but read properly).
    float M[8][8];
    #pragma unroll
    for (int a = 0; a < 8; ++a)
        #pragma unroll
        for (int j = 0; j < 8; ++j)
            M[a][j] = M_init[(((size_t)w * BB_ + b) * NN + 8 * r + a) * NN + 8 * c + j];

    float bias_r[8], bias_c[8];
    #pragma unroll
    for (int a = 0; a < 8; ++a) bias_r[a] = B_gates[w * NN + 8 * r + a];
    #pragma unroll
    for (int j = 0; j < 8; ++j) bias_c[j] = B_gates[w * NN + 8 * c + j];

    float* outp = d_out;                                    // [T][B][n]
    float* Mout = d_out + (size_t)TT * BB_ * NN;            // [K][B][n][n]

    for (int t = 0; t < TT; ++t) {
        const float* base = kvq + ((size_t)t * BB_ + b) * PP;
        const float kt = base[w * 128 + lane];
        const float vt = base[w * 128 + 64 + lane];
        if (w == 0) q_lds[lane] = base[384 + lane];

        // k-norm: wave-wide sum of squares
        float ss = kt * kt;
        #pragma unroll
        for (int m = 1; m < 64; m <<= 1) ss += __shfl_xor(ss, m, 64);
        const float kn = kt / (sqrtf(ss) + 1e-6f);
        kn_lds[w][lane] = kn;
        v_lds[w][lane]  = vt;
        __syncthreads();   // barrier A

        // Gather k_norm slices
        float kno[8], kpc[8], kpr[8];
        #pragma unroll
        for (int j = 0; j < 8; ++j) kno[j] = kn_lds[w][8 * c + j];
        #pragma unroll
        for (int j = 0; j < 8; ++j) kpc[j] = kn_lds[wp][8 * c + j];
        #pragma unroll
        for (int a = 0; a < 8; ++a) kpr[a] = kn_lds[wp][8 * r + a];

        // Fused 3-matvec pass over the 8x8 tile
        float retr[8] = {}, rs[8] = {}, cs[8] = {};
        #pragma unroll
        for (int a = 0; a < 8; ++a) {
            #pragma unroll
            for (int j = 0; j < 8; ++j) {
                const float m_ = M[a][j];
                retr[a] += m_ * kno[j];   // M[w]   @ kn[w]
                rs[a]   += m_ * kpc[j];   // M[w]   @ kn[wp]   (row gate of wp)
                cs[j]   += m_ * kpr[a];   // M[w]^T @ kn[wp]   (col gate of wp)
            }
        }
        // Reduce retr/rs across c (bits 0..2), cs across r (bits 3..5)
        #pragma unroll
        for (int m = 1; m <= 4; m <<= 1) {
            #pragma unroll
            for (int a = 0; a < 8; ++a) {
                retr[a] += __shfl_xor(retr[a], m, 64);
                rs[a]   += __shfl_xor(rs[a], m, 64);
            }
        }
        #pragma unroll
        for (int m = 8; m <= 32; m <<= 1) {
            #pragma unroll
            for (int j = 0; j < 8; ++j) cs[j] += __shfl_xor(cs[j], m, 64);
        }

        float delta[8];
        #pragma unroll
        for (int a = 0; a < 8; ++a) delta[a] = v_lds[w][8 * r + a] - retr[a];

        // Publish gate pre-activations for wave wp (64 distinct elems each)
        rs_lds[wp][8 * r + c] = rs[c];
        cs_lds[wp][8 * c + r] = cs[r];
        __syncthreads();   // barrier B

        // My gates (computed by wave (w+1)%3)
        float rg[8], cg[8];
        #pragma unroll
        for (int a = 0; a < 8; ++a) rg[a] = sigmoidf_(rs_lds[w][8 * r + a] + bias_r[a]);
        #pragma unroll
        for (int j = 0; j < 8; ++j) cg[j] = sigmoidf_(cs_lds[w][8 * c + j] + bias_c[j]);

        // State update: M = rg_i * M * cg_j + delta_i * kn_j
        #pragma unroll
        for (int a = 0; a < 8; ++a) {
            const float da = delta[a];
            const float ra = rg[a];
            #pragma unroll
            for (int j = 0; j < 8; ++j)
                M[a][j] = ra * M[a][j] * cg[j] + da * kno[j];
        }

        // Output: Sq = M_new[0] @ q ; out = SiLU(Sq)   (wave 0 only)
        if (w == 0) {
            float qv[8];
            #pragma unroll
            for (int j = 0; j < 8; ++j) qv[j] = q_lds[8 * c + j];
            float sq[8] = {};
            #pragma unroll
            for (int a = 0; a < 8; ++a)
                #pragma unroll
                for (int j = 0; j < 8; ++j) sq[a] += M[a][j] * qv[j];
            #pragma unroll
            for (int m = 1; m <= 4; m <<= 1) {
                #pragma unroll
                for (int a = 0; a < 8; ++a) sq[a] += __shfl_xor(sq[a], m, 64);
            }
            const float s = sq[c];   // Sq[8r+c] == Sq[lane]
            outp[((size_t)t * BB_ + b) * NN + lane] = s * sigmoidf_(s);
        }
    }

    // Final state write-out: M_final[k][b][i][j]
    #pragma unroll
    for (int a = 0; a < 8; ++a)
        #pragma unroll
        for (int j = 0; j < 8; ++j)
            Mout[(((size_t)w * BB_ + b) * NN + 8 * r + a) * NN + 8 * c + j] = M[a][j];
}

extern "C" void kernel_launch(void* const* d_in, const int* in_sizes, int n_in,
                              void* d_out, int out_size, void* d_ws, size_t ws_size,
                              hipStream_t stream) {
    const float* x       = (const float*)d_in[0];  // (T,B,D)
    const float* M_init  = (const float*)d_in[1];  // (K,B,n,n)
    const float* W_kv    = (const float*)d_in[2];  // (K*2*n, D)
    const float* W_q     = (const float*)d_in[3];  // (n, D)
    const float* B_gates = (const float*)d_in[4];  // (K, n)
    float* out = (float*)d_out;

    float* kvq = (float*)d_ws;   // [T*B][448] = 56 MB

    dim3 ggrid(TT * BB_ / 64, PP / 64);   // 512 x 7
    proj_gemm_kernel<<<ggrid, 256, 0, stream>>>(x, W_kv, W_q, kvq);

    scan_kernel<<<BB_, 192, 0, stream>>>(kvq, M_init, B_gates, out);
}

// Round 2
// 5389.802 us; speedup vs baseline: 1.2535x; 1.2535x over previous
//
#include <hip/hip_runtime.h>
#include <hip/hip_bf16.h>
#include <math.h>

// Problem constants (E83CircularTowerCell): T=2048, B=16, D=1024, n=64, K=3
#define TT 2048
#define BB_ 16
#define DD 1024
#define NN 64
#define KK 3
#define PP 448   // K*2*n + n = 384 + 64

__device__ __forceinline__ float sigmoidf_(float x) {
    return 1.0f / (1.0f + __expf(-x));
}

// LDS-ordering-only barrier: leaves global (vmcnt) loads in flight.
#define LDS_BARRIER() __asm__ volatile("s_waitcnt lgkmcnt(0)\n\ts_barrier" ::: "memory")

__device__ __forceinline__ void load8(float dst[8], const float* p) {
    float4 a = *(const float4*)p;
    float4 b = *(const float4*)(p + 4);
    dst[0] = a.x; dst[1] = a.y; dst[2] = a.z; dst[3] = a.w;
    dst[4] = b.x; dst[5] = b.y; dst[6] = b.z; dst[7] = b.w;
}

// Selective butterfly reduce: 8 partial components per lane, reduced across the
// 8 lanes in the xor-group {mbase,2*mbase,4*mbase}; lane ends with the full sum
// of component s (s in [0,8)). 7 shuffles instead of 24.
__device__ __forceinline__ float sel_reduce8(const float v[8], int s, int mbase) {
    const int s0 = s & 1, s1 = (s >> 1) & 1, s2 = (s >> 2) & 1;
    float k0 = s0 ? v[1] : v[0], d0 = s0 ? v[0] : v[1];
    float k1 = s0 ? v[3] : v[2], d1 = s0 ? v[2] : v[3];
    float k2 = s0 ? v[5] : v[4], d2 = s0 ? v[4] : v[5];
    float k3 = s0 ? v[7] : v[6], d3 = s0 ? v[6] : v[7];
    float a0 = k0 + __shfl_xor(d0, mbase, 64);
    float a1 = k1 + __shfl_xor(d1, mbase, 64);
    float a2 = k2 + __shfl_xor(d2, mbase, 64);
    float a3 = k3 + __shfl_xor(d3, mbase, 64);
    float b0 = s1 ? a1 : a0, e0 = s1 ? a0 : a1;
    float b1 = s1 ? a3 : a2, e1 = s1 ? a2 : a3;
    b0 = b0 + __shfl_xor(e0, 2 * mbase, 64);
    b1 = b1 + __shfl_xor(e1, 2 * mbase, 64);
    float c0 = s2 ? b1 : b0, f0 = s2 ? b0 : b1;
    return c0 + __shfl_xor(f0, 4 * mbase, 64);
}

// ---------------------------------------------------------------------------
// GEMM: kvq[(t*B+b)][p] = sum_d x[t,b,d] * Wcat[p][d]
// ---------------------------------------------------------------------------
__global__ __launch_bounds__(256) void proj_gemm_kernel(
    const float* __restrict__ x,
    const float* __restrict__ Wkv,
    const float* __restrict__ Wq,
    float* __restrict__ kvq)
{
    __shared__ float As[16][68];
    __shared__ float Bs[16][68];

    const int tid = threadIdx.x;
    const int m0 = blockIdx.x * 64;
    const int p0 = blockIdx.y * 64;
    const int tx = tid & 15;
    const int ty = tid >> 4;
    const int lrow = tid >> 2;
    const int lk   = (tid & 3) * 4;

    const int p = p0 + lrow;
    const float* wrow = (p < 384) ? (Wkv + (size_t)p * DD)
                                  : (Wq  + (size_t)(p - 384) * DD);
    const float* arow = x + (size_t)(m0 + lrow) * DD;

    float acc[4][4] = {};

    for (int kb = 0; kb < DD; kb += 16) {
        const float4 a4 = *(const float4*)(arow + kb + lk);
        const float4 b4 = *(const float4*)(wrow + kb + lk);
        __syncthreads();
        As[lk + 0][lrow] = a4.x; As[lk + 1][lrow] = a4.y;
        As[lk + 2][lrow] = a4.z; As[lk + 3][lrow] = a4.w;
        Bs[lk + 0][lrow] = b4.x; Bs[lk + 1][lrow] = b4.y;
        Bs[lk + 2][lrow] = b4.z; Bs[lk + 3][lrow] = b4.w;
        __syncthreads();
        #pragma unroll
        for (int kk = 0; kk < 16; ++kk) {
            const float4 av = *(const float4*)&As[kk][ty * 4];
            const float4 bv = *(const float4*)&Bs[kk][tx * 4];
            const float a[4] = {av.x, av.y, av.z, av.w};
            const float b[4] = {bv.x, bv.y, bv.z, bv.w};
            #pragma unroll
            for (int ia = 0; ia < 4; ++ia)
                #pragma unroll
                for (int ib = 0; ib < 4; ++ib)
                    acc[ia][ib] += a[ia] * b[ib];
        }
    }

    #pragma unroll
    for (int ia = 0; ia < 4; ++ia) {
        float4 v = make_float4(acc[ia][0], acc[ia][1], acc[ia][2], acc[ia][3]);
        *(float4*)&kvq[(size_t)(m0 + ty * 4 + ia) * PP + p0 + tx * 4] = v;
    }
}

// ---------------------------------------------------------------------------
// Normalize all k vectors in-place: k depends only on the projection, not on
// the recurrence, so this is fully parallel. One wave per (t,b,k) row of 64.
// ---------------------------------------------------------------------------
__global__ __launch_bounds__(256) void norm_k_kernel(float* __restrict__ kvq)
{
    const int row  = blockIdx.x * 4 + (threadIdx.x >> 6);
    const int lane = threadIdx.x & 63;
    if (row >= TT * BB_ * KK) return;
    const int tb = row / KK;
    const int k  = row - tb * KK;
    float* p = kvq + (size_t)tb * PP + k * 128;
    const float v = p[lane];
    float ss = v * v;
    #pragma unroll
    for (int m = 1; m < 64; m <<= 1) ss += __shfl_xor(ss, m, 64);
    p[lane] = v / (sqrtf(ss) + 1e-6f);
}

// ---------------------------------------------------------------------------
// Sequential scan. One block per batch b (16 blocks), 3 waves, wave w owns
// M[w] (64x64) in registers: lane (r,c) holds rows 8r..8r+7 x cols 8c..8c+7.
// k is pre-normalized in kvq, so each wave prefetches its own slices AND its
// gate-target's slices straight from global (one step ahead) — no norm chain,
// no kn exchange, ONE lgkm-only barrier per step for the gate sums.
// ---------------------------------------------------------------------------
__global__ __launch_bounds__(192) void scan_kernel(
    const float* __restrict__ kvq,
    const float* __restrict__ M_init,
    const float* __restrict__ B_gates,
    float* __restrict__ d_out)
{
    const int b    = blockIdx.x;
    const int tid  = threadIdx.x;
    const int w    = tid >> 6;        // k index this wave owns
    const int lane = tid & 63;
    const int r    = lane >> 3;
    const int c    = lane & 7;
    const int wp   = (w + 2) % 3;     // gate target (w-1 mod 3)

    __shared__ float rs_lds[2][3][64];
    __shared__ float cs_lds[2][3][64];

    float M[8][8];
    #pragma unroll
    for (int a = 0; a < 8; ++a)
        #pragma unroll
        for (int j = 0; j < 8; ++j)
            M[a][j] = M_init[(((size_t)w * BB_ + b) * NN + 8 * r + a) * NN + 8 * c + j];

    float bias_r[8], bias_c[8];
    #pragma unroll
    for (int a = 0; a < 8; ++a) bias_r[a] = B_gates[w * NN + 8 * r + a];
    #pragma unroll
    for (int j = 0; j < 8; ++j) bias_c[j] = B_gates[w * NN + 8 * c + j];

    float* outp = d_out;                           // [T][B][n]
    float* Mout = d_out + (size_t)TT * BB_ * NN;   // [K][B][n][n]

    // Prefetch t = 0
    float kno[8], kpc[8], kpr[8], vr[8], qv[8];
    {
        const float* base = kvq + (size_t)b * PP;
        load8(kno, base + w * 128 + 8 * c);
        load8(kpc, base + wp * 128 + 8 * c);
        load8(kpr, base + wp * 128 + 8 * r);
        load8(vr,  base + w * 128 + 64 + 8 * r);
        if (w == 0) load8(qv, base + 384 + 8 * c);
    }

    for (int t = 0; t < TT; ++t) {
        // Issue prefetch for t+1 immediately; consumed at end of this body.
        const int tn = (t + 1 < TT) ? t + 1 : t;
        const float* basen = kvq + ((size_t)tn * BB_ + b) * PP;
        float n_kno[8], n_kpc[8], n_kpr[8], n_vr[8], n_qv[8];
        load8(n_kno, basen + w * 128 + 8 * c);
        load8(n_kpc, basen + wp * 128 + 8 * c);
        load8(n_kpr, basen + wp * 128 + 8 * r);
        load8(n_vr,  basen + w * 128 + 64 + 8 * r);
        if (w == 0) load8(n_qv, basen + 384 + 8 * c);

        // Fused 3-matvec over the 8x8 tile
        float retr[8] = {}, rs[8] = {}, cs[8] = {};
        #pragma unroll
        for (int a = 0; a < 8; ++a) {
            #pragma unroll
            for (int j = 0; j < 8; ++j) {
                const float m_ = M[a][j];
                retr[a] += m_ * kno[j];   // M[w]   @ kn[w]
                rs[a]   += m_ * kpc[j];   // M[w]   @ kn[wp]
                cs[j]   += m_ * kpr[a];   // M[w]^T @ kn[wp]
            }
        }

        // retr: full reduce across c-lanes (all 8 components needed)
        #pragma unroll
        for (int m = 1; m <= 4; m <<= 1)
            #pragma unroll
            for (int a = 0; a < 8; ++a)
                retr[a] += __shfl_xor(retr[a], m, 64);

        // rs/cs: selective reduce (only the published component)
        const float rs_val = sel_reduce8(rs, c, 1);   // row 8r+c of wp's row-gate
        const float cs_val = sel_reduce8(cs, r, 8);   // col 8c+r of wp's col-gate

        float delta[8];
        #pragma unroll
        for (int a = 0; a < 8; ++a) delta[a] = vr[a] - retr[a];

        const int pb = t & 1;
        rs_lds[pb][wp][8 * r + c] = rs_val;
        cs_lds[pb][wp][8 * c + r] = cs_val;
        LDS_BARRIER();   // lgkm-only: prefetch loads stay in flight

        float rg[8], cg[8];
        #pragma unroll
        for (int a = 0; a < 8; ++a) rg[a] = sigmoidf_(rs_lds[pb][w][8 * r + a] + bias_r[a]);
        #pragma unroll
        for (int j = 0; j < 8; ++j) cg[j] = sigmoidf_(cs_lds[pb][w][8 * c + j] + bias_c[j]);

        // State update: M = rg_i * M * cg_j + delta_i * kn_j
        #pragma unroll
        for (int a = 0; a < 8; ++a) {
            const float da = delta[a];
            const float ra = rg[a];
            #pragma unroll
            for (int j = 0; j < 8; ++j)
                M[a][j] = ra * M[a][j] * cg[j] + da * kno[j];
        }

        // Output: Sq = M_new[0] @ q ; out = SiLU(Sq)   (wave 0 only)
        if (w == 0) {
            float sq[8] = {};
            #pragma unroll
            for (int a = 0; a < 8; ++a)
                #pragma unroll
                for (int j = 0; j < 8; ++j) sq[a] += M[a][j] * qv[j];
            const float s = sel_reduce8(sq, c, 1);   // Sq[8r+c] == Sq[lane]
            outp[((size_t)t * BB_ + b) * NN + lane] = s * sigmoidf_(s);
        }

        // Rotate prefetch registers
        #pragma unroll
        for (int i = 0; i < 8; ++i) {
            kno[i] = n_kno[i]; kpc[i] = n_kpc[i];
            kpr[i] = n_kpr[i]; vr[i]  = n_vr[i];
        }
        if (w == 0) {
            #pragma unroll
            for (int i = 0; i < 8; ++i) qv[i] = n_qv[i];
        }
    }

    #pragma unroll
    for (int a = 0; a < 8; ++a)
        #pragma unroll
        for (int j = 0; j < 8; ++j)
            Mout[(((size_t)w * BB_ + b) * NN + 8 * r + a) * NN + 8 * c + j] = M[a][j];
}

extern "C" void kernel_launch(void* const* d_in, const int* in_sizes, int n_in,
                              void* d_out, int out_size, void* d_ws, size_t ws_size,
                              hipStream_t stream) {
    const float* x       = (const float*)d_in[0];
    const float* M_init  = (const float*)d_in[1];
    const float* W_kv    = (const float*)d_in[2];
    const float* W_q     = (const float*)d_in[3];
    const float* B_gates = (const float*)d_in[4];
    float* out = (float*)d_out;

    float* kvq = (float*)d_ws;   // [T*B][448] = 56 MB

    dim3 ggrid(TT * BB_ / 64, PP / 64);
    proj_gemm_kernel<<<ggrid, 256, 0, stream>>>(x, W_kv, W_q, kvq);

    norm_k_kernel<<<(TT * BB_ * KK + 3) / 4, 256, 0, stream>>>(kvq);

    scan_kernel<<<BB_, 192, 0, stream>>>(kvq, M_init, B_gates, out);
}

// Round 3
// 4176.960 us; speedup vs baseline: 1.6175x; 1.2904x over previous
//
#include <hip/hip_runtime.h>
#include <hip/hip_bf16.h>
#include <math.h>

// Problem constants (E83CircularTowerCell): T=2048, B=16, D=1024, n=64, K=3
#define TT 2048
#define BB_ 16
#define DD 1024
#define NN 64
#define KK 3
#define PP 448   // K*2*n + n = 384 + 64

__device__ __forceinline__ float sigmoidf_(float x) {
    return 1.0f / (1.0f + __expf(-x));
}

// LDS-ordering-only barrier: leaves global (vmcnt) loads in flight.
#define LDS_BARRIER() __asm__ volatile("s_waitcnt lgkmcnt(0)\n\ts_barrier" ::: "memory")

__device__ __forceinline__ void load4(float d[4], const float* p) {
    float4 t = *(const float4*)p;
    d[0] = t.x; d[1] = t.y; d[2] = t.z; d[3] = t.w;
}

// Selective butterfly: 4 partial components per lane, reduced across the
// 4-lane xor-group {mb, 2mb}; lane ends with full sum of component s,
// where s's bits are the lane's bits log2(mb), log2(2mb). 3 swizzles.
__device__ __forceinline__ float sel_reduce4(const float v[4], int s, int mb) {
    const int s0 = s & 1, s1 = (s >> 1) & 1;
    float k0 = s0 ? v[1] : v[0], d0 = s0 ? v[0] : v[1];
    float k1 = s0 ? v[3] : v[2], d1 = s0 ? v[2] : v[3];
    float a0 = k0 + __shfl_xor(d0, mb, 64);
    float a1 = k1 + __shfl_xor(d1, mb, 64);
    float kb = s1 ? a1 : a0, db = s1 ? a0 : a1;
    return kb + __shfl_xor(db, 2 * mb, 64);
}

// ---------------------------------------------------------------------------
// GEMM: kvq[(t*B+b)][p] = sum_d x[t,b,d] * Wcat[p][d]
// k-tiles (p0 = 0,128,256 hold complete 64-wide k vectors) are L2-normalized
// in the epilogue (fused norm — deletes the separate norm kernel).
// ---------------------------------------------------------------------------
__global__ __launch_bounds__(256) void proj_gemm_kernel(
    const float* __restrict__ x,
    const float* __restrict__ Wkv,
    const float* __restrict__ Wq,
    float* __restrict__ kvq)
{
    __shared__ float As[16][68];
    __shared__ float Bs[16][68];

    const int tid = threadIdx.x;
    const int m0 = blockIdx.x * 64;
    const int p0 = blockIdx.y * 64;
    const int tx = tid & 15;
    const int ty = tid >> 4;
    const int lrow = tid >> 2;
    const int lk   = (tid & 3) * 4;

    const int p = p0 + lrow;
    const float* wrow = (p < 384) ? (Wkv + (size_t)p * DD)
                                  : (Wq  + (size_t)(p - 384) * DD);
    const float* arow = x + (size_t)(m0 + lrow) * DD;

    float acc[4][4] = {};

    for (int kb = 0; kb < DD; kb += 16) {
        const float4 a4 = *(const float4*)(arow + kb + lk);
        const float4 b4 = *(const float4*)(wrow + kb + lk);
        __syncthreads();
        As[lk + 0][lrow] = a4.x; As[lk + 1][lrow] = a4.y;
        As[lk + 2][lrow] = a4.z; As[lk + 3][lrow] = a4.w;
        Bs[lk + 0][lrow] = b4.x; Bs[lk + 1][lrow] = b4.y;
        Bs[lk + 2][lrow] = b4.z; Bs[lk + 3][lrow] = b4.w;
        __syncthreads();
        #pragma unroll
        for (int kk = 0; kk < 16; ++kk) {
            const float4 av = *(const float4*)&As[kk][ty * 4];
            const float4 bv = *(const float4*)&Bs[kk][tx * 4];
            const float a[4] = {av.x, av.y, av.z, av.w};
            const float b[4] = {bv.x, bv.y, bv.z, bv.w};
            #pragma unroll
            for (int ia = 0; ia < 4; ++ia)
                #pragma unroll
                for (int ib = 0; ib < 4; ++ib)
                    acc[ia][ib] += a[ia] * b[ib];
        }
    }

    // Fused k-normalization: row (t,b), cols = the 64 k components of tile.
    if (p0 == 0 || p0 == 128 || p0 == 256) {
        #pragma unroll
        for (int ia = 0; ia < 4; ++ia) {
            float ss = acc[ia][0] * acc[ia][0] + acc[ia][1] * acc[ia][1]
                     + acc[ia][2] * acc[ia][2] + acc[ia][3] * acc[ia][3];
            #pragma unroll
            for (int m = 1; m <= 8; m <<= 1) ss += __shfl_xor(ss, m, 64);
            const float sc = 1.0f / (sqrtf(ss) + 1e-6f);
            #pragma unroll
            for (int ib = 0; ib < 4; ++ib) acc[ia][ib] *= sc;
        }
    }

    #pragma unroll
    for (int ia = 0; ia < 4; ++ia) {
        float4 v = make_float4(acc[ia][0], acc[ia][1], acc[ia][2], acc[ia][3]);
        *(float4*)&kvq[(size_t)(m0 + ty * 4 + ia) * PP + p0 + tx * 4] = v;
    }
}

// ---------------------------------------------------------------------------
// Sequential scan. One block per batch (16 blocks), 12 waves = 768 threads:
// wave (k,q) owns rows 16q..16q+15 of M[k]; lane (tr,tc) owns the 4x4 tile
// rows 16q+4tr.. x cols 4tc.. . Row-direction reductions are in-wave (across
// tc, lane bits 0..3); only the col-gate sum crosses waves (via LDS, folded
// into the single lgkm-only barrier per step). Output Sq=M_new[0]@q_t is
// DEFERRED one step so it fuses into the pre-barrier matvec pass (M register
// reads shared, no post-update tail skew).
// ---------------------------------------------------------------------------
__global__ __launch_bounds__(768) void scan_kernel(
    const float* __restrict__ kvq,
    const float* __restrict__ M_init,
    const float* __restrict__ B_gates,
    float* __restrict__ d_out)
{
    const int b    = blockIdx.x;
    const int tid  = threadIdx.x;
    const int wid  = tid >> 6;        // 0..11
    const int k    = wid >> 2;        // 0..2 : which state matrix
    const int q    = wid & 3;         // row quarter
    const int lane = tid & 63;
    const int tr   = lane >> 4;       // 0..3
    const int tc   = lane & 15;       // 0..15
    const int kp   = (k + 2) % 3;     // gate target (k-1 mod 3)
    const int row0 = 16 * q + 4 * tr;
    const int col0 = 4 * tc;

    __shared__ __align__(16) float rs_lds[2][3][64];
    __shared__ __align__(16) float cs_part[2][3][4][64];  // [pb][k][q][col]

    float M[4][4];
    #pragma unroll
    for (int i = 0; i < 4; ++i)
        load4(M[i], M_init + (((size_t)k * BB_ + b) * NN + row0 + i) * NN + col0);

    float bias_r[4], bias_c[4];
    #pragma unroll
    for (int i = 0; i < 4; ++i) bias_r[i] = B_gates[k * NN + row0 + i];
    #pragma unroll
    for (int j = 0; j < 4; ++j) bias_c[j] = B_gates[k * NN + col0 + j];

    float* outp = d_out;                           // [T][B][n]
    float* Mout = d_out + (size_t)TT * BB_ * NN;   // [K][B][n][n]

    // Current-step vectors (t=0) + q of previous step (t=0 output is skipped,
    // so qp just needs to be finite — init to q_0).
    float knc[4], knr[4], wpc[4], wpr[4], vr[4], qc[4], qp[4];
    {
        const float* base = kvq + (size_t)b * PP;
        load4(knc, base + k * 128 + col0);
        load4(knr, base + k * 128 + row0);
        load4(wpc, base + kp * 128 + col0);
        load4(wpr, base + kp * 128 + row0);
        load4(vr,  base + k * 128 + 64 + row0);
        if (k == 0) { load4(qc, base + 384 + col0); }
        #pragma unroll
        for (int j = 0; j < 4; ++j) qp[j] = (k == 0) ? qc[j] : 0.0f;
    }

    for (int t = 0; t < TT; ++t) {
        // Prefetch t+1 (kept in flight across the lgkm-only barrier).
        const int tn = (t + 1 < TT) ? t + 1 : t;
        const float* basen = kvq + ((size_t)tn * BB_ + b) * PP;
        float n_knc[4], n_knr[4], n_wpc[4], n_wpr[4], n_vr[4], n_qc[4];
        load4(n_knc, basen + k * 128 + col0);
        load4(n_knr, basen + k * 128 + row0);
        load4(n_wpc, basen + kp * 128 + col0);
        load4(n_wpr, basen + kp * 128 + row0);
        load4(n_vr,  basen + k * 128 + 64 + row0);
        if (k == 0) load4(n_qc, basen + 384 + col0);

        // Fused matvec partials over the lane's 4x4 tile.
        float retr_p[4] = {}, rs_p[4] = {}, cs_p[4] = {};
        #pragma unroll
        for (int i = 0; i < 4; ++i) {
            #pragma unroll
            for (int j = 0; j < 4; ++j) {
                const float m_ = M[i][j];
                retr_p[i] += m_ * knc[j];   // M[k]   @ kn[k]
                rs_p[i]   += m_ * wpc[j];   // M[k]   @ kn[kp]
                cs_p[j]   += m_ * wpr[i];   // M[k]^T @ kn[kp]
            }
        }

        // Deferred output for step t-1: M (== M_new of t-1) @ q_{t-1}.
        if (k == 0) {
            float oq_p[4] = {};
            #pragma unroll
            for (int i = 0; i < 4; ++i)
                #pragma unroll
                for (int j = 0; j < 4; ++j) oq_p[i] += M[i][j] * qp[j];
            float oqv = sel_reduce4(oq_p, tc & 3, 1);
            oqv += __shfl_xor(oqv, 4, 64);
            oqv += __shfl_xor(oqv, 8, 64);
            if (t > 0 && tc < 4)
                outp[((size_t)(t - 1) * BB_ + b) * NN + row0 + tc] = oqv * sigmoidf_(oqv);
        }

        // retr: full reduce across tc (all 4 row comps needed by all lanes).
        #pragma unroll
        for (int m = 1; m <= 8; m <<= 1)
            #pragma unroll
            for (int i = 0; i < 4; ++i)
                retr_p[i] += __shfl_xor(retr_p[i], m, 64);

        // rs: comp (tc&3) over 16 tc-lanes (5 swizzles).
        float rsv = sel_reduce4(rs_p, tc & 3, 1);
        rsv += __shfl_xor(rsv, 4, 64);
        rsv += __shfl_xor(rsv, 8, 64);
        // cs: comp tr over the 4 tr-lanes (3 swizzles) -> partial over 16 rows.
        const float csv = sel_reduce4(cs_p, tr, 16);

        float delta[4];
        #pragma unroll
        for (int i = 0; i < 4; ++i) delta[i] = vr[i] - retr_p[i];

        const int pb = t & 1;
        if (tc < 4) rs_lds[pb][kp][row0 + tc] = rsv;      // row 16q+4tr+tc
        cs_part[pb][kp][q][col0 + tr] = csv;              // col 4tc+tr, unique/lane
        LDS_BARRIER();

        // My gates (written by group (k+1)%3).
        float4 rs4 = *(const float4*)&rs_lds[pb][k][row0];
        float4 c0 = *(const float4*)&cs_part[pb][k][0][col0];
        float4 c1 = *(const float4*)&cs_part[pb][k][1][col0];
        float4 c2 = *(const float4*)&cs_part[pb][k][2][col0];
        float4 c3 = *(const float4*)&cs_part[pb][k][3][col0];
        float rg[4], cg[4];
        rg[0] = sigmoidf_(rs4.x + bias_r[0]);
        rg[1] = sigmoidf_(rs4.y + bias_r[1]);
        rg[2] = sigmoidf_(rs4.z + bias_r[2]);
        rg[3] = sigmoidf_(rs4.w + bias_r[3]);
        cg[0] = sigmoidf_(c0.x + c1.x + c2.x + c3.x + bias_c[0]);
        cg[1] = sigmoidf_(c0.y + c1.y + c2.y + c3.y + bias_c[1]);
        cg[2] = sigmoidf_(c0.z + c1.z + c2.z + c3.z + bias_c[2]);
        cg[3] = sigmoidf_(c0.w + c1.w + c2.w + c3.w + bias_c[3]);

        // Update: M = rg_i * M * cg_j + delta_i * kn_j
        #pragma unroll
        for (int i = 0; i < 4; ++i) {
            const float di = delta[i];
            const float ri = rg[i];
            #pragma unroll
            for (int j = 0; j < 4; ++j)
                M[i][j] = ri * (M[i][j] * cg[j]) + di * knc[j];
        }

        // Rotate prefetch.
        #pragma unroll
        for (int j = 0; j < 4; ++j) {
            qp[j] = qc[j];
            knc[j] = n_knc[j]; knr[j] = n_knr[j];
            wpc[j] = n_wpc[j]; wpr[j] = n_wpr[j];
            vr[j] = n_vr[j];   qc[j] = n_qc[j];
        }
    }

    // Flush deferred output for t = TT-1 (qp == q_{TT-1} after final rotate).
    if (k == 0) {
        float oq_p[4] = {};
        #pragma unroll
        for (int i = 0; i < 4; ++i)
            #pragma unroll
            for (int j = 0; j < 4; ++j) oq_p[i] += M[i][j] * qp[j];
        float oqv = sel_reduce4(oq_p, tc & 3, 1);
        oqv += __shfl_xor(oqv, 4, 64);
        oqv += __shfl_xor(oqv, 8, 64);
        if (tc < 4)
            outp[((size_t)(TT - 1) * BB_ + b) * NN + row0 + tc] = oqv * sigmoidf_(oqv);
    }

    // Final state write-out.
    #pragma unroll
    for (int i = 0; i < 4; ++i) {
        float4 v = make_float4(M[i][0], M[i][1], M[i][2], M[i][3]);
        *(float4*)&Mout[(((size_t)k * BB_ + b) * NN + row0 + i) * NN + col0] = v;
    }
}

extern "C" void kernel_launch(void* const* d_in, const int* in_sizes, int n_in,
                              void* d_out, int out_size, void* d_ws, size_t ws_size,
                              hipStream_t stream) {
    const float* x       = (const float*)d_in[0];
    const float* M_init  = (const float*)d_in[1];
    const float* W_kv    = (const float*)d_in[2];
    const float* W_q     = (const float*)d_in[3];
    const float* B_gates = (const float*)d_in[4];
    float* out = (float*)d_out;

    float* kvq = (float*)d_ws;   // [T*B][448] = 56 MB, k rows pre-normalized

    dim3 ggrid(TT * BB_ / 64, PP / 64);
    proj_gemm_kernel<<<ggrid, 256, 0, stream>>>(x, W_kv, W_q, kvq);

    scan_kernel<<<BB_, 768, 0, stream>>>(kvq, M_init, B_gates, out);
}